// Round 3
// baseline (936.815 us; speedup 1.0000x reference)
//
#include <hip/hip_runtime.h>

#define NUM_USERS_C 500000
#define EPS_F 1e-12f

// ---------------------------------------------------------------------------
// Pass 1 over edges: self-loop flags + per-dest count. The counting atomic's
// return value IS the CSR slot -> store it so scatter needs no atomics.
// ---------------------------------------------------------------------------
__global__ void k_edgeprep(const int* __restrict__ row, const int* __restrict__ col,
                           int* __restrict__ flags, int* __restrict__ cnt,
                           int* __restrict__ slot, int E) {
    int e = blockIdx.x * blockDim.x + threadIdx.x;
    if (e < E) {
        int r = row[e], c = col[e];
        if (r == c) flags[r] = 1;          // benign race, all store 1
        slot[e] = atomicAdd(&cnt[c], 1);   // slot within dest node's CSR row
    }
}

// ---------------------------------------------------------------------------
// Two-level exclusive scan: cnt[0..N) -> rowptr[0..N]
// ---------------------------------------------------------------------------
__global__ __launch_bounds__(256) void k_blocksum(const int* __restrict__ cnt,
                                                  int* __restrict__ bsum, int N) {
    __shared__ int s[256];
    int i = blockIdx.x * 256 + threadIdx.x;
    s[threadIdx.x] = (i < N) ? cnt[i] : 0;
    __syncthreads();
    for (int d = 128; d > 0; d >>= 1) {
        if (threadIdx.x < d) s[threadIdx.x] += s[threadIdx.x + d];
        __syncthreads();
    }
    if (threadIdx.x == 0) bsum[blockIdx.x] = s[0];
}

// Single block: exclusive scan of NB (<=1024) block sums; also writes rowptr[N].
__global__ __launch_bounds__(1024) void k_scanbsum(const int* __restrict__ bsum,
                                                   int* __restrict__ boff,
                                                   int* __restrict__ rowptr,
                                                   int NB, int N) {
    __shared__ int s[1024];
    int t = threadIdx.x;
    int v = (t < NB) ? bsum[t] : 0;
    s[t] = v;
    __syncthreads();
    for (int d = 1; d < 1024; d <<= 1) {
        int u = (t >= d) ? s[t - d] : 0;
        __syncthreads();
        s[t] += u;
        __syncthreads();
    }
    if (t < NB) boff[t] = s[t] - v;       // exclusive prefix of block sums
    if (t == 1023) rowptr[N] = s[1023];   // grand total
}

__global__ __launch_bounds__(256) void k_rowptr(const int* __restrict__ cnt,
                                                const int* __restrict__ boff,
                                                int* __restrict__ rowptr, int N) {
    __shared__ int s[256];
    int i = blockIdx.x * 256 + threadIdx.x;
    int v = (i < N) ? cnt[i] : 0;
    s[threadIdx.x] = v;
    __syncthreads();
    for (int d = 1; d < 256; d <<= 1) {
        int u = (threadIdx.x >= d) ? s[threadIdx.x - d] : 0;
        __syncthreads();
        s[threadIdx.x] += u;
        __syncthreads();
    }
    if (i < N) rowptr[i] = boff[blockIdx.x] + s[threadIdx.x] - v;  // exclusive
}

// Scatter edges into CSR order (atomic-free): emeta[pos] = {src_row, raw_w}
__global__ void k_scatter(const int* __restrict__ row, const int* __restrict__ col,
                          const float* __restrict__ w, const int* __restrict__ slot,
                          const int* __restrict__ rowptr,
                          int2* __restrict__ emeta, int E) {
    int e = blockIdx.x * blockDim.x + threadIdx.x;
    if (e < E) {
        int c = col[e];
        int pos = rowptr[c] + slot[e];
        emeta[pos] = make_int2(row[e], __float_as_int(w[e]));
    }
}

// Weighted degree from CSR (coalesced, atomic-free) -> dinfo = {dinv, loop_w}
__global__ __launch_bounds__(256) void k_deg(const int* __restrict__ rowptr,
                                             const int2* __restrict__ emeta,
                                             const int* __restrict__ flags,
                                             float2* __restrict__ dinfo, int N) {
    int lane = threadIdx.x & 63;
    int node = blockIdx.x * 4 + (threadIdx.x >> 6);
    if (node >= N) return;
    int beg = rowptr[node], end = rowptr[node + 1];
    float s = 0.0f;
    for (int i = beg + lane; i < end; i += 64)
        s += __int_as_float(emeta[i].y);
    #pragma unroll
    for (int off = 32; off > 0; off >>= 1) s += __shfl_xor(s, off, 64);
    float lw = flags[node] ? 0.0f : 1.0f;
    float d = s + lw;
    float di = (d > 0.0f) ? rsqrtf(fmaxf(d, EPS_F)) : 0.0f;
    if (lane == 0) dinfo[node] = make_float2(di, lw);
}

// ---------------------------------------------------------------------------
// Compaction: split batch positions into user list / item list.
// Order within lists is irrelevant (each entry writes only its own row).
// ---------------------------------------------------------------------------
__global__ __launch_bounds__(256) void k_classify(const int* __restrict__ batch_nodes,
                                                  int* __restrict__ ucnt, int* __restrict__ icnt,
                                                  int* __restrict__ upos, int* __restrict__ ubid,
                                                  int* __restrict__ ipos, int* __restrict__ iit,
                                                  int N) {
    int i = blockIdx.x * 256 + threadIdx.x;
    if (i >= N) return;
    int idx = batch_nodes[i];
    if (idx < NUM_USERS_C) {
        int p = atomicAdd(ucnt, 1);       // wave-coalesced by compiler
        upos[p] = i; ubid[p] = idx;
    } else {
        int p = atomicAdd(icnt, 1);
        ipos[p] = i; iit[p] = idx - NUM_USERS_C;
    }
}

// ---------------------------------------------------------------------------
// User features: wave per user (lane = dim). Pure gather + l2norm, memory-bound.
// ---------------------------------------------------------------------------
__global__ __launch_bounds__(256) void k_feat_user(
    const int* __restrict__ ucnt, const int* __restrict__ upos, const int* __restrict__ ubid,
    const float* __restrict__ user_emb, const float2* __restrict__ dinfo,
    float* __restrict__ xt, float* __restrict__ acc)
{
    int lane = threadIdx.x & 63;
    int gwid = blockIdx.x * 4 + (threadIdx.x >> 6);
    int stride = gridDim.x * 4;
    int uc = *ucnt;
    for (int u = gwid; u < uc; u += stride) {
        int n = upos[u];                   // wave-uniform
        int id = ubid[u];
        float val = user_emb[(size_t)id * 64 + lane];
        float ss = val * val;
        #pragma unroll
        for (int off = 32; off > 0; off >>= 1) ss += __shfl_xor(ss, off, 64);
        float scale = 1.0f / fmaxf(sqrtf(ss), EPS_F);
        val *= scale;
        float di = dinfo[n].x;
        acc[(size_t)n * 64 + lane] = val;
        xt[(size_t)n * 64 + lane] = di * val;
    }
}

// ---------------------------------------------------------------------------
// Item features: LANE = ITEM. Each lane computes its item's full 64-d
// projection with acc[64] in registers. W[k,d] is wave-uniform -> s_load,
// so the inner op is a single v_fmac with SGPR operand. No LDS, no shfl.
// ---------------------------------------------------------------------------
__device__ __forceinline__ void fma8(float* __restrict__ a64,
                                     const float* __restrict__ proj_w,
                                     float4 x0, float4 x1, int kb) {
    const float xs[8] = {x0.x, x0.y, x0.z, x0.w, x1.x, x1.y, x1.z, x1.w};
    #pragma unroll
    for (int jj = 0; jj < 8; jj++) {
        const float* wr = proj_w + (size_t)(kb + jj) * 64;   // uniform
        float av = xs[jj];
        #pragma unroll
        for (int d = 0; d < 64; d++) a64[d] = fmaf(av, wr[d], a64[d]);
    }
}

__device__ __forceinline__ float4 avg2(float4 a, float4 b) {
    float4 r;
    r.x = 0.5f * (a.x + b.x); r.y = 0.5f * (a.y + b.y);
    r.z = 0.5f * (a.z + b.z); r.w = 0.5f * (a.w + b.w);
    return r;
}

__global__ __launch_bounds__(256) void k_feat_item(
    const int* __restrict__ icnt, const int* __restrict__ ipos, const int* __restrict__ iit,
    const float* __restrict__ artist_emb, const float* __restrict__ album_emb,
    const float* __restrict__ audio_emb,
    const int* __restrict__ artist_ids, const int* __restrict__ album_ids,
    const float* __restrict__ proj_w, const float* __restrict__ proj_b,
    const float2* __restrict__ dinfo,
    float* __restrict__ xt, float* __restrict__ acc)
{
    const int lane = threadIdx.x & 63;
    const int gwid = blockIdx.x * 4 + (threadIdx.x >> 6);
    const int ic = *icnt;
    const int base = gwid * 64;
    if (base >= ic) return;
    int j = base + lane;
    bool live = j < ic;
    int jj = live ? j : (ic - 1);          // dead lanes duplicate a real item
    int n  = ipos[jj];
    int it = iit[jj];
    int aid = artist_ids[it];
    int bid = album_ids[it];
    const float4* __restrict__ A = (const float4*)(audio_emb  + (size_t)it  * 64);
    const float4* __restrict__ R = (const float4*)(artist_emb + (size_t)aid * 64);
    const float4* __restrict__ S = (const float4*)(album_emb  + (size_t)bid * 64);

    float a[64];
    #pragma unroll
    for (int d = 0; d < 64; d++) a[d] = proj_b[d];   // uniform s_load init

    // ---- audio half: W rows 0..63, register-double-buffered gathers ----
    float4 c0 = A[0], c1 = A[1];
    #pragma unroll 1
    for (int kb = 0; kb < 7; kb++) {
        float4 p0 = A[(kb + 1) * 2], p1 = A[(kb + 1) * 2 + 1];
        fma8(a, proj_w, c0, c1, kb * 8);
        c0 = p0; c1 = p1;
    }
    // prefetch meta block 0 under the last audio block
    float4 r0 = R[0], r1 = R[1], s0 = S[0], s1 = S[1];
    fma8(a, proj_w, c0, c1, 56);

    // ---- meta half: W rows 64..127 ----
    #pragma unroll 1
    for (int kb = 0; kb < 7; kb++) {
        float4 nr0 = R[(kb + 1) * 2], nr1 = R[(kb + 1) * 2 + 1];
        float4 ns0 = S[(kb + 1) * 2], ns1 = S[(kb + 1) * 2 + 1];
        fma8(a, proj_w, avg2(r0, s0), avg2(r1, s1), 64 + kb * 8);
        r0 = nr0; r1 = nr1; s0 = ns0; s1 = ns1;
    }
    fma8(a, proj_w, avg2(r0, s0), avg2(r1, s1), 120);

    // ---- lane-local l2norm + scatter write (16B chunks per item row) ----
    float ss0 = 0.0f, ss1 = 0.0f, ss2 = 0.0f, ss3 = 0.0f;
    #pragma unroll
    for (int d = 0; d < 64; d += 4) {
        ss0 = fmaf(a[d + 0], a[d + 0], ss0);
        ss1 = fmaf(a[d + 1], a[d + 1], ss1);
        ss2 = fmaf(a[d + 2], a[d + 2], ss2);
        ss3 = fmaf(a[d + 3], a[d + 3], ss3);
    }
    float ss = (ss0 + ss1) + (ss2 + ss3);
    float scale = 1.0f / fmaxf(sqrtf(ss), EPS_F);
    float di = dinfo[n].x;
    if (live) {
        float4* ao = (float4*)(acc + (size_t)n * 64);
        float4* xo = (float4*)(xt + (size_t)n * 64);
        #pragma unroll
        for (int d4 = 0; d4 < 16; d4++) {
            float4 v;
            v.x = a[d4 * 4 + 0] * scale; v.y = a[d4 * 4 + 1] * scale;
            v.z = a[d4 * 4 + 2] * scale; v.w = a[d4 * 4 + 3] * scale;
            ao[d4] = v;
            float4 w;
            w.x = v.x * di; w.y = v.y * di; w.z = v.z * di; w.w = v.w * di;
            xo[d4] = w;
        }
    }
}

// ---------------------------------------------------------------------------
// CSR propagation over x~ = dinv*x:  t[c] = sum_e w*x~[r] + lw*x~[c]
//   x_next = dinv[c]*t   (added to acc);   x~_next = dinv[c]*x_next
// ---------------------------------------------------------------------------
__device__ __forceinline__ float prop_accum(
    const int* __restrict__ rowptr, const int2* __restrict__ emeta,
    const float* __restrict__ xs, int node, int lane, float lw)
{
    int beg = rowptr[node], end = rowptr[node + 1];
    float a = lw * xs[(size_t)node * 64 + lane];
    for (int base = beg; base < end; base += 64) {
        int chunk = min(64, end - base);
        int2 m = make_int2(0, 0);
        if (lane < chunk) m = emeta[base + lane];   // coalesced 8B/lane
        int j = 0;
        for (; j + 8 <= chunk; j += 8) {
            int r0 = __shfl(m.x, j + 0); float w0 = __int_as_float(__shfl(m.y, j + 0));
            int r1 = __shfl(m.x, j + 1); float w1 = __int_as_float(__shfl(m.y, j + 1));
            int r2 = __shfl(m.x, j + 2); float w2 = __int_as_float(__shfl(m.y, j + 2));
            int r3 = __shfl(m.x, j + 3); float w3 = __int_as_float(__shfl(m.y, j + 3));
            int r4 = __shfl(m.x, j + 4); float w4 = __int_as_float(__shfl(m.y, j + 4));
            int r5 = __shfl(m.x, j + 5); float w5 = __int_as_float(__shfl(m.y, j + 5));
            int r6 = __shfl(m.x, j + 6); float w6 = __int_as_float(__shfl(m.y, j + 6));
            int r7 = __shfl(m.x, j + 7); float w7 = __int_as_float(__shfl(m.y, j + 7));
            float v0 = xs[(size_t)r0 * 64 + lane];
            float v1 = xs[(size_t)r1 * 64 + lane];
            float v2 = xs[(size_t)r2 * 64 + lane];
            float v3 = xs[(size_t)r3 * 64 + lane];
            float v4 = xs[(size_t)r4 * 64 + lane];
            float v5 = xs[(size_t)r5 * 64 + lane];
            float v6 = xs[(size_t)r6 * 64 + lane];
            float v7 = xs[(size_t)r7 * 64 + lane];
            a = fmaf(w0, v0, a); a = fmaf(w1, v1, a);
            a = fmaf(w2, v2, a); a = fmaf(w3, v3, a);
            a = fmaf(w4, v4, a); a = fmaf(w5, v5, a);
            a = fmaf(w6, v6, a); a = fmaf(w7, v7, a);
        }
        for (; j < chunk; j++) {
            int r = __shfl(m.x, j); float wv = __int_as_float(__shfl(m.y, j));
            a = fmaf(wv, xs[(size_t)r * 64 + lane], a);
        }
    }
    return a;
}

__global__ __launch_bounds__(256) void k_prop(
    const int* __restrict__ rowptr, const int2* __restrict__ emeta,
    const float2* __restrict__ dinfo,
    const float* __restrict__ xs, float* __restrict__ xd,
    float* __restrict__ acc, int N)
{
    int lane = threadIdx.x & 63;
    int node = blockIdx.x * 4 + (threadIdx.x >> 6);
    if (node >= N) return;
    float2 dn = dinfo[node];
    float t = prop_accum(rowptr, emeta, xs, node, lane, dn.y);
    float xnext = dn.x * t;                       // actual x_{l+1}
    acc[(size_t)node * 64 + lane] += xnext;
    xd[(size_t)node * 64 + lane] = dn.x * xnext;  // x~_{l+1}
}

// Last layer: fold acc-add, /4, l2norm; write out only.
__global__ __launch_bounds__(256) void k_prop_final(
    const int* __restrict__ rowptr, const int2* __restrict__ emeta,
    const float2* __restrict__ dinfo,
    const float* __restrict__ xs, float* __restrict__ acc_out, int N)
{
    int lane = threadIdx.x & 63;
    int node = blockIdx.x * 4 + (threadIdx.x >> 6);
    if (node >= N) return;
    float2 dn = dinfo[node];
    float t = prop_accum(rowptr, emeta, xs, node, lane, dn.y);
    float xnext = dn.x * t;
    float v = (acc_out[(size_t)node * 64 + lane] + xnext) * 0.25f;
    float ss = v * v;
    #pragma unroll
    for (int off = 32; off > 0; off >>= 1) ss += __shfl_xor(ss, off, 64);
    float scale = 1.0f / fmaxf(sqrtf(ss), EPS_F);
    acc_out[(size_t)node * 64 + lane] = v * scale;
}

// ---------------------------------------------------------------------------
extern "C" void kernel_launch(void* const* d_in, const int* in_sizes, int n_in,
                              void* d_out, int out_size, void* d_ws, size_t ws_size,
                              hipStream_t stream) {
    const int*   batch_nodes = (const int*)d_in[0];
    const int*   edge_index  = (const int*)d_in[1];
    const float* edge_w      = (const float*)d_in[2];
    const float* user_emb    = (const float*)d_in[3];
    const float* artist_emb  = (const float*)d_in[4];
    const float* album_emb   = (const float*)d_in[5];
    const float* audio_emb   = (const float*)d_in[6];
    const int*   artist_ids  = (const int*)d_in[7];
    const int*   album_ids   = (const int*)d_in[8];
    const float* proj_w      = (const float*)d_in[9];
    const float* proj_b      = (const float*)d_in[10];

    const int N = in_sizes[0];
    const int E = in_sizes[2];
    const int* row = edge_index;
    const int* col = edge_index + E;
    float* out = (float*)d_out;   // doubles as acc

    const int NB = (N + 255) / 256;   // blocks for the two-level scan

    // workspace carve-up
    char* ws = (char*)d_ws;
    int*    flags  = (int*)ws;    ws += (size_t)N * sizeof(int);
    int*    cnt    = (int*)ws;    ws += (size_t)N * sizeof(int);
    int*    rowptr = (int*)ws;    ws += (size_t)(N + 1) * sizeof(int);
    int*    bsum   = (int*)ws;    ws += (size_t)NB * sizeof(int);
    int*    boff   = (int*)ws;    ws += (size_t)NB * sizeof(int);
    int*    cnts2  = (int*)ws;    ws += 2 * sizeof(int);   // {ucnt, icnt}
    ws = (char*)(((uintptr_t)ws + 15) & ~(uintptr_t)15);
    float2* dinfo  = (float2*)ws; ws += (size_t)N * sizeof(float2);
    int2*   emeta  = (int2*)ws;   ws += (size_t)E * sizeof(int2);
    float*  xA     = (float*)ws;  ws += (size_t)N * 64 * sizeof(float);
    float*  xB     = (float*)ws;  ws += (size_t)N * 64 * sizeof(float);

    // Aliases inside xB (xB is first written by k_prop #1, after all these die):
    //  slot: live edgeprep -> scatter;  lists: live classify -> feat kernels.
    int* slot = (int*)xB;
    int* upos = (int*)xB;
    int* ubid = upos + N;
    int* ipos = ubid + N;
    int* iit  = ipos + N;

    hipMemsetAsync(flags, 0, (size_t)N * sizeof(int), stream);
    hipMemsetAsync(cnt, 0, (size_t)N * sizeof(int), stream);

    const int TB = 256;

    k_edgeprep<<<(E + TB - 1) / TB, TB, 0, stream>>>(row, col, flags, cnt, slot, E);
    k_blocksum<<<NB, 256, 0, stream>>>(cnt, bsum, N);
    k_scanbsum<<<1, 1024, 0, stream>>>(bsum, boff, rowptr, NB, N);
    k_rowptr<<<NB, 256, 0, stream>>>(cnt, boff, rowptr, N);
    k_scatter<<<(E + TB - 1) / TB, TB, 0, stream>>>(row, col, edge_w, slot,
                                                    rowptr, emeta, E);

    int pblocks = (N + 3) / 4;  // 4 waves (nodes) per 256-thread block
    k_deg<<<pblocks, 256, 0, stream>>>(rowptr, emeta, flags, dinfo, N);

    // slot[] is dead now; reuse xB space for the compaction lists.
    hipMemsetAsync(cnts2, 0, 2 * sizeof(int), stream);
    k_classify<<<NB, 256, 0, stream>>>(batch_nodes, &cnts2[0], &cnts2[1],
                                       upos, ubid, ipos, iit, N);

    k_feat_user<<<1024, 256, 0, stream>>>(&cnts2[0], upos, ubid, user_emb, dinfo, xA, out);

    int iwaves = (N + 63) / 64;              // worst case: all nodes are items
    int iblocks = (iwaves + 3) / 4;
    k_feat_item<<<iblocks, 256, 0, stream>>>(&cnts2[1], ipos, iit,
                                             artist_emb, album_emb, audio_emb,
                                             artist_ids, album_ids, proj_w, proj_b,
                                             dinfo, xA, out);

    k_prop<<<pblocks, 256, 0, stream>>>(rowptr, emeta, dinfo, xA, xB, out, N);
    k_prop<<<pblocks, 256, 0, stream>>>(rowptr, emeta, dinfo, xB, xA, out, N);
    k_prop_final<<<pblocks, 256, 0, stream>>>(rowptr, emeta, dinfo, xA, out, N);
}

// Round 5
// 925.874 us; speedup vs baseline: 1.0118x; 1.0118x over previous
//
#include <hip/hip_runtime.h>

#define NUM_USERS_C 500000
#define EPS_F 1e-12f

// ---------------------------------------------------------------------------
// Pass 1 over edges: self-loop flags + per-dest count. The counting atomic's
// return value IS the CSR slot -> store it so scatter needs no atomics.
// ---------------------------------------------------------------------------
__global__ void k_edgeprep(const int* __restrict__ row, const int* __restrict__ col,
                           int* __restrict__ flags, int* __restrict__ cnt,
                           int* __restrict__ slot, int E) {
    int e = blockIdx.x * blockDim.x + threadIdx.x;
    if (e < E) {
        int r = row[e], c = col[e];
        if (r == c) flags[r] = 1;          // benign race, all store 1
        slot[e] = atomicAdd(&cnt[c], 1);   // slot within dest node's CSR row
    }
}

// ---------------------------------------------------------------------------
// Two-level exclusive scan: cnt[0..N) -> rowptr[0..N]
// ---------------------------------------------------------------------------
__global__ __launch_bounds__(256) void k_blocksum(const int* __restrict__ cnt,
                                                  int* __restrict__ bsum, int N) {
    __shared__ int s[256];
    int i = blockIdx.x * 256 + threadIdx.x;
    s[threadIdx.x] = (i < N) ? cnt[i] : 0;
    __syncthreads();
    for (int d = 128; d > 0; d >>= 1) {
        if (threadIdx.x < d) s[threadIdx.x] += s[threadIdx.x + d];
        __syncthreads();
    }
    if (threadIdx.x == 0) bsum[blockIdx.x] = s[0];
}

// Single block: exclusive scan of NB (<=1024) block sums; also writes rowptr[N].
__global__ __launch_bounds__(1024) void k_scanbsum(const int* __restrict__ bsum,
                                                   int* __restrict__ boff,
                                                   int* __restrict__ rowptr,
                                                   int NB, int N) {
    __shared__ int s[1024];
    int t = threadIdx.x;
    int v = (t < NB) ? bsum[t] : 0;
    s[t] = v;
    __syncthreads();
    for (int d = 1; d < 1024; d <<= 1) {
        int u = (t >= d) ? s[t - d] : 0;
        __syncthreads();
        s[t] += u;
        __syncthreads();
    }
    if (t < NB) boff[t] = s[t] - v;       // exclusive prefix of block sums
    if (t == 1023) rowptr[N] = s[1023];   // grand total
}

__global__ __launch_bounds__(256) void k_rowptr(const int* __restrict__ cnt,
                                                const int* __restrict__ boff,
                                                int* __restrict__ rowptr, int N) {
    __shared__ int s[256];
    int i = blockIdx.x * 256 + threadIdx.x;
    int v = (i < N) ? cnt[i] : 0;
    s[threadIdx.x] = v;
    __syncthreads();
    for (int d = 1; d < 256; d <<= 1) {
        int u = (threadIdx.x >= d) ? s[threadIdx.x - d] : 0;
        __syncthreads();
        s[threadIdx.x] += u;
        __syncthreads();
    }
    if (i < N) rowptr[i] = boff[blockIdx.x] + s[threadIdx.x] - v;  // exclusive
}

// Scatter edges into CSR order (atomic-free): emeta[pos] = {src_row, raw_w}
__global__ void k_scatter(const int* __restrict__ row, const int* __restrict__ col,
                          const float* __restrict__ w, const int* __restrict__ slot,
                          const int* __restrict__ rowptr,
                          int2* __restrict__ emeta, int E) {
    int e = blockIdx.x * blockDim.x + threadIdx.x;
    if (e < E) {
        int c = col[e];
        int pos = rowptr[c] + slot[e];
        emeta[pos] = make_int2(row[e], __float_as_int(w[e]));
    }
}

// Weighted degree from CSR (coalesced, atomic-free) -> dinfo = {dinv, loop_w}
__global__ __launch_bounds__(256) void k_deg(const int* __restrict__ rowptr,
                                             const int2* __restrict__ emeta,
                                             const int* __restrict__ flags,
                                             float2* __restrict__ dinfo, int N) {
    int lane = threadIdx.x & 63;
    int node = blockIdx.x * 4 + (threadIdx.x >> 6);
    if (node >= N) return;
    int beg = rowptr[node], end = rowptr[node + 1];
    float s = 0.0f;
    for (int i = beg + lane; i < end; i += 64)
        s += __int_as_float(emeta[i].y);
    #pragma unroll
    for (int off = 32; off > 0; off >>= 1) s += __shfl_xor(s, off, 64);
    float lw = flags[node] ? 0.0f : 1.0f;
    float d = s + lw;
    float di = (d > 0.0f) ? rsqrtf(fmaxf(d, EPS_F)) : 0.0f;
    if (lane == 0) dinfo[node] = make_float2(di, lw);
}

// ---------------------------------------------------------------------------
// Compaction: split batch positions into user list / item list.
// ---------------------------------------------------------------------------
__global__ __launch_bounds__(256) void k_classify(const int* __restrict__ batch_nodes,
                                                  int* __restrict__ ucnt, int* __restrict__ icnt,
                                                  int* __restrict__ upos, int* __restrict__ ubid,
                                                  int* __restrict__ ipos, int* __restrict__ iit,
                                                  int N) {
    int i = blockIdx.x * 256 + threadIdx.x;
    if (i >= N) return;
    int idx = batch_nodes[i];
    if (idx < NUM_USERS_C) {
        int p = atomicAdd(ucnt, 1);       // wave-coalesced by compiler
        upos[p] = i; ubid[p] = idx;
    } else {
        int p = atomicAdd(icnt, 1);
        ipos[p] = i; iit[p] = idx - NUM_USERS_C;
    }
}

// ---------------------------------------------------------------------------
// User features: wave per user (lane = dim). Pure gather + l2norm.
// Writes only x~0 = dinv * x0.
// ---------------------------------------------------------------------------
__global__ __launch_bounds__(256) void k_feat_user(
    const int* __restrict__ ucnt, const int* __restrict__ upos, const int* __restrict__ ubid,
    const float* __restrict__ user_emb, const float2* __restrict__ dinfo,
    float* __restrict__ xt)
{
    int lane = threadIdx.x & 63;
    int gwid = blockIdx.x * 4 + (threadIdx.x >> 6);
    int stride = gridDim.x * 4;
    int uc = *ucnt;
    for (int u = gwid; u < uc; u += stride) {
        int n = upos[u];                   // wave-uniform
        int id = ubid[u];
        float val = user_emb[(size_t)id * 64 + lane];
        float ss = val * val;
        #pragma unroll
        for (int off = 32; off > 0; off >>= 1) ss += __shfl_xor(ss, off, 64);
        float scale = 1.0f / fmaxf(sqrtf(ss), EPS_F);
        xt[(size_t)n * 64 + lane] = dinfo[n].x * val * scale;
    }
}

// ---------------------------------------------------------------------------
// Item features: lane = dim, 8 items per wave from the compacted item list.
// One Ws ds_read feeds 16 fmas (8 items x 2-way split accumulator); readlane
// broadcast of loaded features. No wasted matvecs (all-item groups).
// ---------------------------------------------------------------------------
__device__ __forceinline__ float bcast(float v, int k) {
    return __int_as_float(__builtin_amdgcn_readlane(__float_as_int(v), k));
}

__global__ __launch_bounds__(256) void k_feat_item(
    const int* __restrict__ icnt, const int* __restrict__ ipos, const int* __restrict__ iit,
    const float* __restrict__ artist_emb, const float* __restrict__ album_emb,
    const float* __restrict__ audio_emb,
    const int* __restrict__ artist_ids, const int* __restrict__ album_ids,
    const float* __restrict__ proj_w, const float* __restrict__ proj_b,
    const float2* __restrict__ dinfo,
    float* __restrict__ xt)
{
    __shared__ float Ws[128 * 64];
    for (int i = threadIdx.x; i < 128 * 64; i += blockDim.x)
        Ws[i] = proj_w[i];
    __syncthreads();

    const int lane = threadIdx.x & 63;
    const int wid = threadIdx.x >> 6;
    const int ic = *icnt;
    const int ngroups = (ic + 7) / 8;
    const int gstride = gridDim.x * 4;
    const float bias = proj_b[lane];

    for (int g = blockIdx.x * 4 + wid; g < ngroups; g += gstride) {
        int base = g * 8;
        int cnt8 = min(8, ic - base);
        float vlo[8], vhi[8];
        int nn[8];
        #pragma unroll
        for (int j = 0; j < 8; ++j) {
            int jj = (j < cnt8) ? base + j : base;   // dup first item for dead slots
            int it = iit[jj];                        // wave-uniform s_load
            nn[j] = ipos[jj];
            int aid = artist_ids[it];
            int bid = album_ids[it];
            vlo[j] = audio_emb[(size_t)it * 64 + lane];
            vhi[j] = 0.5f * (artist_emb[(size_t)aid * 64 + lane] +
                             album_emb[(size_t)bid * 64 + lane]);
        }

        float sA[8], sB[8];
        #pragma unroll
        for (int j = 0; j < 8; ++j) { sA[j] = bias; sB[j] = 0.0f; }

        #pragma unroll
        for (int k = 0; k < 64; k += 2) {
            float w0 = Ws[k * 64 + lane];
            float w1 = Ws[(k + 1) * 64 + lane];
            #pragma unroll
            for (int j = 0; j < 8; ++j) {
                sA[j] = fmaf(bcast(vlo[j], k),     w0, sA[j]);
                sB[j] = fmaf(bcast(vlo[j], k + 1), w1, sB[j]);
            }
        }
        #pragma unroll
        for (int k = 0; k < 64; k += 2) {
            float w0 = Ws[(64 + k) * 64 + lane];
            float w1 = Ws[(65 + k) * 64 + lane];
            #pragma unroll
            for (int j = 0; j < 8; ++j) {
                sA[j] = fmaf(bcast(vhi[j], k),     w0, sA[j]);
                sB[j] = fmaf(bcast(vhi[j], k + 1), w1, sB[j]);
            }
        }

        #pragma unroll
        for (int j = 0; j < 8; ++j) {
            if (j < cnt8) {
                float val = sA[j] + sB[j];
                float ss = val * val;
                #pragma unroll
                for (int off = 32; off > 0; off >>= 1) ss += __shfl_xor(ss, off, 64);
                float scale = 1.0f / fmaxf(sqrtf(ss), EPS_F);
                int n = nn[j];
                xt[(size_t)n * 64 + lane] = dinfo[n].x * val * scale;
            }
        }
    }
}

// ---------------------------------------------------------------------------
// CSR propagation over x~ = dinv*x. Since every layer's x~ carries the SAME
// per-node factor dinv, and the output is l2-normalized per node, we never
// need acc = sum(x_l): l2norm(sum x~_l) == l2norm(sum x_l). Props write only
// x~; prop2 folds the running per-node sum (coalesced own-row, race-free).
// ---------------------------------------------------------------------------
__device__ __forceinline__ float prop_edges(
    const int* __restrict__ rowptr, const int2* __restrict__ emeta,
    const float* __restrict__ xs, int node, int lane)
{
    int beg = rowptr[node], end = rowptr[node + 1];
    float a = 0.0f;
    for (int base = beg; base < end; base += 64) {
        int chunk = min(64, end - base);
        int2 m = make_int2(0, 0);
        if (lane < chunk) m = emeta[base + lane];   // coalesced 8B/lane
        int j = 0;
        for (; j + 16 <= chunk; j += 16) {          // 16 loads in flight
            int rr[16]; float ww[16], vv[16];
            #pragma unroll
            for (int t = 0; t < 16; t++) {
                rr[t] = __shfl(m.x, j + t);
                ww[t] = __int_as_float(__shfl(m.y, j + t));
            }
            #pragma unroll
            for (int t = 0; t < 16; t++) vv[t] = xs[(size_t)rr[t] * 64 + lane];
            #pragma unroll
            for (int t = 0; t < 16; t++) a = fmaf(ww[t], vv[t], a);
        }
        for (; j + 8 <= chunk; j += 8) {
            int rr[8]; float ww[8], vv[8];
            #pragma unroll
            for (int t = 0; t < 8; t++) {
                rr[t] = __shfl(m.x, j + t);
                ww[t] = __int_as_float(__shfl(m.y, j + t));
            }
            #pragma unroll
            for (int t = 0; t < 8; t++) vv[t] = xs[(size_t)rr[t] * 64 + lane];
            #pragma unroll
            for (int t = 0; t < 8; t++) a = fmaf(ww[t], vv[t], a);
        }
        for (; j < chunk; j++) {
            int r = __shfl(m.x, j); float wv = __int_as_float(__shfl(m.y, j));
            a = fmaf(wv, xs[(size_t)r * 64 + lane], a);
        }
    }
    return a;
}

// Layer 1: read x~0, write x~1 only.
__global__ __launch_bounds__(256) void k_prop1(
    const int* __restrict__ rowptr, const int2* __restrict__ emeta,
    const float2* __restrict__ dinfo,
    const float* __restrict__ xs, float* __restrict__ xd, int N)
{
    int lane = threadIdx.x & 63;
    int node = blockIdx.x * 4 + (threadIdx.x >> 6);
    if (node >= N) return;
    float2 dn = dinfo[node];
    float self = xs[(size_t)node * 64 + lane];
    float t = dn.y * self + prop_edges(rowptr, emeta, xs, node, lane);
    xd[(size_t)node * 64 + lane] = (dn.x * dn.x) * t;   // x~1
}

// Layer 2: read x~1, write x~2; fold psum = x~0 + x~1 + x~2 into x0 buffer.
__global__ __launch_bounds__(256) void k_prop2(
    const int* __restrict__ rowptr, const int2* __restrict__ emeta,
    const float2* __restrict__ dinfo,
    const float* __restrict__ xs, float* __restrict__ xd,
    float* __restrict__ ps, int N)
{
    int lane = threadIdx.x & 63;
    int node = blockIdx.x * 4 + (threadIdx.x >> 6);
    if (node >= N) return;
    float2 dn = dinfo[node];
    size_t o = (size_t)node * 64 + lane;
    float s1 = xs[o];                                    // x~1 own row
    float t = dn.y * s1 + prop_edges(rowptr, emeta, xs, node, lane);
    float x2t = (dn.x * dn.x) * t;                       // x~2
    xd[o] = x2t;
    ps[o] = ps[o] + s1 + x2t;                            // x~0 + x~1 + x~2
}

// Layer 3: read x~2, add x~3 to psum, l2norm, write out.
__global__ __launch_bounds__(256) void k_prop_final(
    const int* __restrict__ rowptr, const int2* __restrict__ emeta,
    const float2* __restrict__ dinfo,
    const float* __restrict__ xs, const float* __restrict__ ps,
    float* __restrict__ out, int N)
{
    int lane = threadIdx.x & 63;
    int node = blockIdx.x * 4 + (threadIdx.x >> 6);
    if (node >= N) return;
    float2 dn = dinfo[node];
    size_t o = (size_t)node * 64 + lane;
    float s2 = xs[o];                                    // x~2 own row
    float t = dn.y * s2 + prop_edges(rowptr, emeta, xs, node, lane);
    float x3t = (dn.x * dn.x) * t;                       // x~3
    float v = ps[o] + x3t;                               // dinv_n * sum(x_l)
    float ss = v * v;
    #pragma unroll
    for (int off = 32; off > 0; off >>= 1) ss += __shfl_xor(ss, off, 64);
    float scale = 1.0f / fmaxf(sqrtf(ss), EPS_F);
    out[o] = v * scale;                                  // scale-invariant
}

// ---------------------------------------------------------------------------
extern "C" void kernel_launch(void* const* d_in, const int* in_sizes, int n_in,
                              void* d_out, int out_size, void* d_ws, size_t ws_size,
                              hipStream_t stream) {
    const int*   batch_nodes = (const int*)d_in[0];
    const int*   edge_index  = (const int*)d_in[1];
    const float* edge_w      = (const float*)d_in[2];
    const float* user_emb    = (const float*)d_in[3];
    const float* artist_emb  = (const float*)d_in[4];
    const float* album_emb   = (const float*)d_in[5];
    const float* audio_emb   = (const float*)d_in[6];
    const int*   artist_ids  = (const int*)d_in[7];
    const int*   album_ids   = (const int*)d_in[8];
    const float* proj_w      = (const float*)d_in[9];
    const float* proj_b      = (const float*)d_in[10];

    const int N = in_sizes[0];
    const int E = in_sizes[2];
    const int* row = edge_index;
    const int* col = edge_index + E;
    float* out = (float*)d_out;        // scratch for x~1, then final output

    const int NB = (N + 255) / 256;

    // workspace carve-up
    char* ws = (char*)d_ws;
    int*    flags  = (int*)ws;    ws += (size_t)N * sizeof(int);
    int*    cnt    = (int*)ws;    ws += (size_t)N * sizeof(int);
    int*    rowptr = (int*)ws;    ws += (size_t)(N + 1) * sizeof(int);
    int*    bsum   = (int*)ws;    ws += (size_t)NB * sizeof(int);
    int*    boff   = (int*)ws;    ws += (size_t)NB * sizeof(int);
    int*    cnts2  = (int*)ws;    ws += 2 * sizeof(int);   // {ucnt, icnt}
    ws = (char*)(((uintptr_t)ws + 15) & ~(uintptr_t)15);
    float2* dinfo  = (float2*)ws; ws += (size_t)N * sizeof(float2);
    int2*   emeta  = (int2*)ws;   ws += (size_t)E * sizeof(int2);
    float*  xA     = (float*)ws;  ws += (size_t)N * 64 * sizeof(float);  // x~0 -> psum
    float*  xB     = (float*)ws;  ws += (size_t)N * 64 * sizeof(float);  // x~2

    // Aliases inside xB (dead before k_prop2 writes xB):
    //  slot: live edgeprep -> scatter;  lists: live classify -> feat kernels.
    int* slot = (int*)xB;
    int* upos = (int*)xB;
    int* ubid = upos + N;
    int* ipos = ubid + N;
    int* iit  = ipos + N;

    hipMemsetAsync(flags, 0, (size_t)N * sizeof(int), stream);
    hipMemsetAsync(cnt, 0, (size_t)N * sizeof(int), stream);

    const int TB = 256;

    k_edgeprep<<<(E + TB - 1) / TB, TB, 0, stream>>>(row, col, flags, cnt, slot, E);
    k_blocksum<<<NB, 256, 0, stream>>>(cnt, bsum, N);
    k_scanbsum<<<1, 1024, 0, stream>>>(bsum, boff, rowptr, NB, N);
    k_rowptr<<<NB, 256, 0, stream>>>(cnt, boff, rowptr, N);
    k_scatter<<<(E + TB - 1) / TB, TB, 0, stream>>>(row, col, edge_w, slot,
                                                    rowptr, emeta, E);

    int pblocks = (N + 3) / 4;  // 4 waves (nodes) per 256-thread block
    k_deg<<<pblocks, 256, 0, stream>>>(rowptr, emeta, flags, dinfo, N);

    // slot[] is dead now; reuse xB space for the compaction lists.
    hipMemsetAsync(cnts2, 0, 2 * sizeof(int), stream);
    k_classify<<<NB, 256, 0, stream>>>(batch_nodes, &cnts2[0], &cnts2[1],
                                       upos, ubid, ipos, iit, N);

    k_feat_user<<<1024, 256, 0, stream>>>(&cnts2[0], upos, ubid, user_emb, dinfo, xA);
    k_feat_item<<<4096, 256, 0, stream>>>(&cnts2[1], ipos, iit,
                                          artist_emb, album_emb, audio_emb,
                                          artist_ids, album_ids, proj_w, proj_b,
                                          dinfo, xA);

    // x~0 in xA; prop1 -> x~1 in out; prop2 -> x~2 in xB, psum in xA; final -> out
    k_prop1<<<pblocks, 256, 0, stream>>>(rowptr, emeta, dinfo, xA, out, N);
    k_prop2<<<pblocks, 256, 0, stream>>>(rowptr, emeta, dinfo, out, xB, xA, N);
    k_prop_final<<<pblocks, 256, 0, stream>>>(rowptr, emeta, dinfo, xB, xA, out, N);
}